// Round 6
// baseline (108.971 us; speedup 1.0000x reference)
//
#include <hip/hip_runtime.h>

// Problem constants
#define HW   576      // 24*24 pixels
#define CC   512      // channels
#define PW   30       // padded H/W
#define PPK  1024     // padded p rows (900 real + pad)
#define WLS  1048     // Wl row stride (1024 + 24: stride%32 dwords = 12 -> 2-way free)

typedef float f32x4 __attribute__((ext_vector_type(4)));
typedef short s16x8 __attribute__((ext_vector_type(8)));

__device__ __forceinline__ unsigned short f2bf(float f) {
    unsigned u = __float_as_uint(f);                      // RNE fp32->bf16
    return (unsigned short)((u + 0x7FFFu + ((u >> 16) & 1u)) >> 16);
}
__device__ __forceinline__ float bf2f(unsigned short h) {
    return __uint_as_float((unsigned)h << 16);
}
// reflect-pad row map; p>=900 -> zero row 576 of xT
__device__ __forceinline__ int smapf(int p) {
    if (p >= 900) return 576;
    const int y = p / PW, xw = p - y * PW;
    int iy = y - 3;  iy = (iy < 0) ? -iy : (iy > 23 ? 46 - iy : iy);
    int ix = xw - 3; ix = (ix < 0) ? -ix : (ix > 23 ? 46 - ix : ix);
    return iy * 24 + ix;
}

// Workspace byte offsets
#define OFF_QT 0u         // bf16 [8][576][64]
#define OFF_KT 589824u    // bf16 [8][1024][64]
#define OFF_VP 1638400u   // bf16 [8][64][1024]
#define OFF_XT 2686976u   // bf16 [577][512] (row 576 = zeros)
#define OFF_WB 3277824u   // bf16 [3][512][512]

// ---------------------------------------------------------------------------
// Kernel 0: build xT (bf16 transpose of x, LDS-tiled 64x64, + zero row) and
// wb (bf16 copy of Wq/Wk/Wv). grid 457 blocks x 256.
// ---------------------------------------------------------------------------
__global__ __launch_bounds__(256) void cvtT(
    const float* __restrict__ x,
    const float* __restrict__ Wq, const float* __restrict__ Wk,
    const float* __restrict__ Wv,
    unsigned short* __restrict__ xT, unsigned short* __restrict__ wb)
{
    const int b = blockIdx.x, t = threadIdx.x;
    if (b < 72) {                                  // transpose: 9 pix-tiles x 8 chan-tiles
        __shared__ float tile[64][65];             // [chan][pix]; stride 65 -> 2-way free
        const int pt = b % 9, ct = b / 9;
        const int p0 = pt * 64, c0 = ct * 64;
        const int tr = t >> 4, tc4 = (t & 15) * 4;
        #pragma unroll
        for (int cr = 0; cr < 4; ++cr) {
            const int row = cr * 16 + tr;          // chan_local
            const float4 v = *(const float4*)&x[(size_t)(c0 + row) * HW + p0 + tc4];
            tile[row][tc4 + 0] = v.x;
            tile[row][tc4 + 1] = v.y;
            tile[row][tc4 + 2] = v.z;
            tile[row][tc4 + 3] = v.w;
        }
        __syncthreads();
        #pragma unroll
        for (int cr = 0; cr < 4; ++cr) {
            const int prow = cr * 16 + tr;         // pix_local
            ushort4 o;
            o.x = f2bf(tile[tc4 + 0][prow]);
            o.y = f2bf(tile[tc4 + 1][prow]);
            o.z = f2bf(tile[tc4 + 2][prow]);
            o.w = f2bf(tile[tc4 + 3][prow]);
            *(ushort4*)&xT[(size_t)(p0 + prow) * CC + c0 + tc4] = o;
        }
    } else if (b == 72) {                          // zero row 576
        if (t < 128) *(ushort4*)&xT[(size_t)576 * CC + t * 4] = (ushort4){0, 0, 0, 0};
    } else {                                       // W convert: 384 blocks x 2048 elems
        const int wi = (b - 73) * 2048 + t * 8;
        const int sel = wi >> 18, off = wi & 262143;
        const float* src = (sel == 0) ? Wq : (sel == 1) ? Wk : Wv;
        const float4 v0 = *(const float4*)&src[off];
        const float4 v1 = *(const float4*)&src[off + 4];
        ushort4 o0, o1;
        o0.x = f2bf(v0.x); o0.y = f2bf(v0.y); o0.z = f2bf(v0.z); o0.w = f2bf(v0.w);
        o1.x = f2bf(v1.x); o1.y = f2bf(v1.y); o1.z = f2bf(v1.z); o1.w = f2bf(v1.w);
        *(ushort4*)&wb[wi]     = o0;
        *(ushort4*)&wb[wi + 4] = o1;
    }
}

// ---------------------------------------------------------------------------
// Kernel 1: Q/K/V projections, barrier-free MFMA (unchanged from R5-verified).
// ---------------------------------------------------------------------------
__global__ __launch_bounds__(256) void qkv_direct(
    const unsigned short* __restrict__ xT, const unsigned short* __restrict__ wb,
    const float* __restrict__ bq, const float* __restrict__ bk,
    const float* __restrict__ bv,
    unsigned short* __restrict__ qT, unsigned short* __restrict__ kT,
    unsigned short* __restrict__ vP)
{
    const int t = threadIdx.x;
    const int w = blockIdx.x * 4 + (t >> 6);
    const int lane = t & 63, fr = lane & 15, u = lane >> 4;

    int sel, m0, n0;
    if (w < 576)       { sel = 0; m0 = (w >> 4) << 4;               n0 = (w & 15) << 5; }
    else if (w < 1600) { const int k = w - 576;  sel = 1; m0 = (k >> 4) << 4; n0 = (k & 15) << 5; }
    else               { const int k = w - 1600; sel = 2; m0 = (k >> 5) << 4; n0 = (k & 31) << 5; }

    const unsigned short *A, *B;
    int ar, bn0, bn1;
    if (sel == 0)      { A = xT;          B = wb;          ar = m0 + fr;
                         bn0 = n0 + fr;          bn1 = n0 + 16 + fr; }
    else if (sel == 1) { A = xT;          B = wb + 262144; ar = smapf(m0 + fr);
                         bn0 = n0 + fr;          bn1 = n0 + 16 + fr; }
    else               { A = wb + 524288; B = xT;          ar = m0 + fr;
                         bn0 = smapf(n0 + fr);   bn1 = smapf(n0 + 16 + fr); }

    const unsigned short* Ap  = A + (size_t)ar  * CC + u * 8;
    const unsigned short* Bp0 = B + (size_t)bn0 * CC + u * 8;
    const unsigned short* Bp1 = B + (size_t)bn1 * CC + u * 8;

    f32x4 acc0 = (f32x4){0.f, 0.f, 0.f, 0.f};
    f32x4 acc1 = (f32x4){0.f, 0.f, 0.f, 0.f};
    #pragma unroll 8
    for (int k0 = 0; k0 < CC; k0 += 32) {
        const s16x8 a  = *(const s16x8*)(Ap  + k0);
        const s16x8 b0 = *(const s16x8*)(Bp0 + k0);
        const s16x8 b1 = *(const s16x8*)(Bp1 + k0);
        acc0 = __builtin_amdgcn_mfma_f32_16x16x32_bf16(a, b0, acc0, 0, 0, 0);
        acc1 = __builtin_amdgcn_mfma_f32_16x16x32_bf16(a, b1, acc1, 0, 0, 0);
    }

    // epilogue: C/D layout col(fr)=n, row(u*4+r)=m
    #pragma unroll
    for (int ni = 0; ni < 2; ++ni) {
        const f32x4 acc = ni ? acc1 : acc0;
        #pragma unroll
        for (int r = 0; r < 4; ++r) {
            const int m = m0 + u * 4 + r;
            const int n = n0 + ni * 16 + fr;
            if (sel == 0) {
                qT[((size_t)(n >> 6) * HW + m) * 64 + (n & 63)] = f2bf(acc[r] + bq[n]);
            } else if (sel == 1) {
                kT[((size_t)(n >> 6) * PPK + m) * 64 + (n & 63)] = f2bf(acc[r] + bk[n]);
            } else {
                vP[((size_t)(m >> 6) * 64 + (m & 63)) * PPK + n] = f2bf(acc[r] + bv[m]);
            }
        }
    }
}

// ---------------------------------------------------------------------------
// Kernel 2: FUSED attention (QK + weighted softmax + PV + epilogue in one
// block). Block = (16q, head): grid (36, 8) = 288 blocks x 512 threads
// (8 waves). Wave w owns p rows [w*128, w*128+128) for QK; for PV wave w
// owns d-tile (w&3) over p-half (w>>2), pairwise-combined through LDS.
// Softmax stats are in-block LDS reductions -> no partials, no combine
// kernel, no Op/mP/lP global round-trip. LDS ~47 KB -> 3 blocks/CU.
// ---------------------------------------------------------------------------
__global__ __launch_bounds__(512) void attn4(
    const unsigned short* __restrict__ qT, const unsigned short* __restrict__ kT,
    const unsigned short* __restrict__ vP, const float* __restrict__ x,
    const float* __restrict__ gamma, float* __restrict__ out)
{
    const int hd = blockIdx.y;
    const int q0 = blockIdx.x * 16;
    const int t  = threadIdx.x;
    const int w = t >> 6, lane = t & 63;
    const int fr = lane & 15, u = lane >> 4;

    __shared__ float cnt_s[PPK];                            // 4 KB
    __shared__ __align__(16) unsigned short Wl[16 * WLS];   // 32.75 KB weights [q][p]
    __shared__ float mw[128], lw[128], red[16];
    __shared__ __align__(16) float Osc[8][64][4];           // 8 KB PV partials

    // multiplicity table (0 for pad p >= 900)
    for (int i = t; i < PPK; i += 512) {
        float c = 0.f;
        if (i < 900) {
            const int y = i / PW, xw = i - y * PW;
            int cy = y + 1;  if (PW - y  < cy) cy = PW - y;  if (cy > 7) cy = 7;
            int cx = xw + 1; if (PW - xw < cx) cx = PW - xw; if (cx > 7) cx = 7;
            c = (float)(cy * cx);
        }
        cnt_s[i] = c;
    }

    // q B-frags (same 16 q rows for every wave; L2 broadcast)
    const unsigned short* qrow = qT + ((size_t)hd * HW + q0 + fr) * 64 + u * 8;
    const s16x8 b0 = *(const s16x8*)qrow;
    const s16x8 b1 = *(const s16x8*)(qrow + 32);

    // ---- QK: wave w does 8 E^T tiles (16p x 16q) over p = w*128.. ----
    f32x4 e[8];
    #pragma unroll
    for (int t8 = 0; t8 < 8; ++t8) {
        const unsigned short* krow =
            kT + ((size_t)hd * PPK + w * 128 + t8 * 16 + fr) * 64 + u * 8;
        const s16x8 a0 = *(const s16x8*)krow;
        const s16x8 a1 = *(const s16x8*)(krow + 32);
        f32x4 a = (f32x4){0.f, 0.f, 0.f, 0.f};
        a = __builtin_amdgcn_mfma_f32_16x16x32_bf16(a0, b0, a, 0, 0, 0);
        a = __builtin_amdgcn_mfma_f32_16x16x32_bf16(a1, b1, a, 0, 0, 0);
        e[t8] = a;
    }

    // per-q max across this wave's 128 p (in-lane regs share q=fr), then block
    float m = -1e30f;
    #pragma unroll
    for (int t8 = 0; t8 < 8; ++t8)
        #pragma unroll
        for (int r = 0; r < 4; ++r) m = fmaxf(m, e[t8][r]);
    m = fmaxf(m, __shfl_xor(m, 16));
    m = fmaxf(m, __shfl_xor(m, 32));
    if (lane < 16) mw[w * 16 + lane] = m;
    __syncthreads();                               // also covers cnt_s fill
    float mq = mw[fr];
    #pragma unroll
    for (int w2 = 1; w2 < 8; ++w2) mq = fmaxf(mq, mw[w2 * 16 + fr]);

    // weights = cnt * exp(e - mq) -> bf16 Wl; per-q sum
    float sum = 0.f;
    #pragma unroll
    for (int t8 = 0; t8 < 8; ++t8) {
        const int pb = w * 128 + t8 * 16 + u * 4;
        unsigned short wb4[4];
        #pragma unroll
        for (int r = 0; r < 4; ++r) {
            const float wv = cnt_s[pb + r] * __expf(e[t8][r] - mq);
            sum += wv;
            wb4[r] = f2bf(wv);
        }
        const unsigned lo = (unsigned)wb4[0] | ((unsigned)wb4[1] << 16);
        const unsigned hi = (unsigned)wb4[2] | ((unsigned)wb4[3] << 16);
        *(unsigned long long*)&Wl[fr * WLS + pb] =
            (unsigned long long)lo | ((unsigned long long)hi << 32);
    }
    sum += __shfl_xor(sum, 16);
    sum += __shfl_xor(sum, 32);
    if (lane < 16) lw[w * 16 + lane] = sum;
    __syncthreads();                               // Wl + lw visible
    if (t < 16) {
        float l = lw[t];
        #pragma unroll
        for (int w2 = 1; w2 < 8; ++w2) l += lw[w2 * 16 + t];
        red[t] = l;
    }

    // ---- PV: wave w -> d-tile dt = w&3 over p-half hp = w>>2 (512 p) ----
    const int dt = w & 3, hp = w >> 2;
    f32x4 o = (f32x4){0.f, 0.f, 0.f, 0.f};
    const unsigned short* vrow =
        vP + ((size_t)hd * 64 + dt * 16 + fr) * PPK + hp * 512 + u * 8;
    const unsigned short* wrow = &Wl[fr * WLS + hp * 512 + u * 8];
    #pragma unroll
    for (int c = 0; c < 16; ++c) {
        const s16x8 aw  = *(const s16x8*)(wrow + c * 32);
        const s16x8 bv2 = *(const s16x8*)(vrow + c * 32);
        o = __builtin_amdgcn_mfma_f32_16x16x32_bf16(aw, bv2, o, 0, 0, 0);
    }
    *(float4*)&Osc[w][lane][0] = make_float4(o[0], o[1], o[2], o[3]);
    __syncthreads();                               // Osc + red visible

    // ---- Epilogue: out = gamma * (O/l) + x ; 2 outputs/thread ----
    {
        const int d = t >> 3, qp = (t & 7) * 2;
        const int dt2 = d >> 4, frd = d & 15;
        const float g = gamma[0];
        float2 r2;
        #pragma unroll
        for (int j = 0; j < 2; ++j) {
            const int q = qp + j;
            const int ln = (q >> 2) * 16 + frd, rq = q & 3;
            const float val = Osc[dt2][ln][rq] + Osc[dt2 + 4][ln][rq];
            (&r2.x)[j] = (g / red[q]) * val;
        }
        const size_t gi = (size_t)(hd * 64 + d) * HW + q0 + qp;
        const float2 xi = *(const float2*)&x[gi];
        r2.x += xi.x;
        r2.y += xi.y;
        *(float2*)&out[gi] = r2;
    }
}

// ---------------------------------------------------------------------------
extern "C" void kernel_launch(void* const* d_in, const int* in_sizes, int n_in,
                              void* d_out, int out_size, void* d_ws, size_t ws_size,
                              hipStream_t stream) {
    const float* x     = (const float*)d_in[0];
    const float* Wq    = (const float*)d_in[1];
    const float* bq    = (const float*)d_in[2];
    const float* Wk    = (const float*)d_in[3];
    const float* bk    = (const float*)d_in[4];
    const float* Wv    = (const float*)d_in[5];
    const float* bv    = (const float*)d_in[6];
    const float* gamma = (const float*)d_in[7];
    float* out = (float*)d_out;

    char* wsb = (char*)d_ws;
    unsigned short* qT = (unsigned short*)(wsb + OFF_QT);
    unsigned short* kT = (unsigned short*)(wsb + OFF_KT);
    unsigned short* vP = (unsigned short*)(wsb + OFF_VP);
    unsigned short* xT = (unsigned short*)(wsb + OFF_XT);
    unsigned short* wb = (unsigned short*)(wsb + OFF_WB);

    cvtT<<<dim3(457), 256, 0, stream>>>(x, Wq, Wk, Wv, xT, wb);
    qkv_direct<<<dim3(656), 256, 0, stream>>>(xT, wb, bq, bk, bv, qT, kT, vP);
    attn4<<<dim3(36, 8), 512, 0, stream>>>(qT, kT, vP, x, gamma, out);
}